// Round 11
// baseline (153.603 us; speedup 1.0000x reference)
//
#include <hip/hip_runtime.h>

// EventWarping: contrast-maximization loss for event-camera flow.
// flow [B,2,H,W] f32, ts [B,N,1] f32, ys/xs/pol [B,N] i32 -> scalar f32.
//
// Round 11: r10's 2048-block scatter was neutral (occupancy 36->54% but time
// flat — 5th falsified scatter theory). Reverted to r8 scatter config, and
// UN-fused smooth from scatter: the fused kernel was ~= sum of both (they
// compete for the same thread slots). Smooth now rides in the bound launch
// (tiny LDS, low BW -> real idle capacity). accum can't host it: 4x34KB
// LDS packing leaves only 24KB.

constexpr int H = 480, W = 640, HW = H * W;
constexpr int B = 8, N = 131072;
constexpr float FLOW_SCALING = 640.0f;
constexpr float EPS = 1e-9f;

constexpr int TH = 32, TW = 64;            // tile size
constexpr int TILES_Y = H / TH;            // 15
constexpr int TILES_X = W / TW;            // 10
constexpr int TILES = TILES_Y * TILES_X;   // 150
constexpr int NBINS = B * 2 * TILES;       // 2400 (b, tref, tile)
constexpr int CAP = 3072;                  // slots per bin (mean ~873, ~74 sigma)

constexpr float PSCALE = 262144.0f;        // 2^18 fixed point
constexpr float EPS_S = PSCALE * EPS;      // eps in scaled domain

constexpr int BND_BLK = 56;                // bound blocks per job
constexpr int SM_BLK = 512;                // smooth blocks (fused into bound)
constexpr int SC_BLOCKS = 1024;            // scatter grid (128 per batch)

// Per-tile edge strip: seg0 ly=0 (65), seg1 ly=TH (65), seg2 lx=0,ly=1..TH-1
// (31), seg3 lx=TW,ly=1..TH-1 (31) => 192 entries x {pos,neg} u64.
constexpr int EDGE_PX = 2 * (TW + 1) + 2 * (TH - 1);   // 192

// Line-pixel index space per job: row-lines k*W+x, col-lines TILES_Y*W+m*H+y.
constexpr int BPX = TILES_Y * W + TILES_X * H;   // 14400

// Workspace layout:
constexpr size_t ACCL_OFF = 0;                                        // f64[16][150]
constexpr size_t ACCN_OFF = ACCL_OFF + (size_t)16 * TILES * 8;
constexpr size_t BNDL_OFF = ACCN_OFF + (size_t)16 * TILES * 8;
constexpr size_t BNDN_OFF = BNDL_OFF + (size_t)16 * BND_BLK * 8;
constexpr size_t SMP_OFF  = BNDN_OFF + (size_t)16 * BND_BLK * 8;
constexpr size_t CUR_OFF  = SMP_OFF + (size_t)SM_BLK * 4 * 8;
constexpr size_t BNDE_OFF = CUR_OFF + (size_t)NBINS * 4;
constexpr size_t BNDE_BYTES = (size_t)NBINS * EDGE_PX * 2 * 8;        // 7.37MB
constexpr size_t ITEMS_OFF = BNDE_OFF + BNDE_BYTES;                   // +59MB items

__device__ inline double blk_reduce(double v, double* sm) {
    __syncthreads();
    #pragma unroll
    for (int o = 32; o > 0; o >>= 1) v += __shfl_down(v, o, 64);
    int lane = threadIdx.x & 63;
    int wid  = threadIdx.x >> 6;
    if (lane == 0) sm[wid] = v;
    __syncthreads();
    double r = 0.0;
    if (threadIdx.x == 0) {
        int nw = (int)(blockDim.x >> 6);
        for (int w2 = 0; w2 < nw; ++w2) r += sm[w2];
    }
    return r;  // thread 0 only
}

// Local bin id (tref*TILES + tile) from the PACKED payload, so count and
// placement can never disagree.
__device__ inline int bin_from_payload(unsigned long long v) {
    int t = (int)(v & 1);
    int fyi = (int)((unsigned)(v >> 40) >> 12) - 512;
    int fxi = (int)(((unsigned)(v >> 16) & 0xFFFFFFu) >> 12) - 512;
    int cy = min(max(fyi, 0), H - 1);
    int cx = min(max(fxi, 0), W - 1);
    return t * TILES + (cy >> 5) * TILES_X + (cx >> 6);
}

__device__ inline float charb(float a, float b) {
    return sqrtf(a * a + b * b + 1e-6f);
}

// Pure scatter: batch = blockIdx&7 (XCD pin), 1024 events/block (4/thread,
// int4/float4 loads). Payload u64: [63:40] (wy+512)*4096 rn,
// [39:16] (wx+512)*4096 rn, [15:2] sw*16383 rn, [1] pol, [0] tref.
__global__ __launch_bounds__(256) void scatter_kernel(
    const float* __restrict__ flow, const float* __restrict__ ts,
    const int* __restrict__ ys, const int* __restrict__ xs,
    const int* __restrict__ pol,
    unsigned long long* __restrict__ items, unsigned* __restrict__ cursors) {
    __shared__ unsigned scount[2 * TILES];
    __shared__ unsigned sbase[2 * TILES];
    __shared__ unsigned scur[2 * TILES];
    int tid = threadIdx.x;
    for (int i = tid; i < 2 * TILES; i += 256) { scount[i] = 0; scur[i] = 0; }
    __syncthreads();

    int b = blockIdx.x & 7;
    int chunk = blockIdx.x >> 3;          // 0..127
    int eb0 = b * N + chunk * 1024;       // 16B aligned
    const float* fb = flow + (size_t)b * 2 * HW;

    int4   yv = ((const int4*)(ys + eb0))[tid];
    int4   xv = ((const int4*)(xs + eb0))[tid];
    int4   pv = ((const int4*)(pol + eb0))[tid];
    float4 tv = ((const float4*)(ts + eb0))[tid];
    int y4[4] = {yv.x, yv.y, yv.z, yv.w};
    int x4[4] = {xv.x, xv.y, xv.z, xv.w};
    int p4[4] = {pv.x, pv.y, pv.z, pv.w};
    float t4[4] = {tv.x, tv.y, tv.z, tv.w};

    float fx4[4], fy4[4];
    #pragma unroll
    for (int k = 0; k < 4; ++k) {
        int flat = y4[k] * W + x4[k];
        fx4[k] = fb[flat];
        fy4[k] = fb[HW + flat];
    }

    unsigned long long pay[8];
    int bin8[8];
    #pragma unroll
    for (int k = 0; k < 4; ++k) {
        float t0 = t4[k];
        #pragma unroll
        for (int t = 0; t < 2; ++t) {
            float dt = (t == 0 ? 1.0f : 0.0f) - t0;
            float sw = (t == 0) ? t0 : 1.0f - t0;
            float wy = (float)y4[k] + dt * fy4[k] * FLOW_SCALING;
            float wx = (float)x4[k] + dt * fx4[k] * FLOW_SCALING;
            unsigned long long v = ~0ull;  // sentinel = invalid
            int binl = -1;
            if (wy >= -1.0f && wy < (float)H && wx >= -1.0f && wx < (float)W) {
                unsigned uy = __float2uint_rn((wy + 512.0f) * 4096.0f);
                unsigned ux = __float2uint_rn((wx + 512.0f) * 4096.0f);
                unsigned usw = __float2uint_rn(sw * 16383.0f);
                v = ((unsigned long long)uy << 40) |
                    ((unsigned long long)ux << 16) |
                    ((unsigned long long)usw << 2) |
                    ((unsigned long long)(p4[k] != 0) << 1) |
                    (unsigned long long)t;
                binl = bin_from_payload(v);
                atomicAdd(&scount[binl], 1u);
            }
            pay[k * 2 + t] = v;
            bin8[k * 2 + t] = binl;
        }
    }
    __syncthreads();
    for (int i = tid; i < 2 * TILES; i += 256) {
        unsigned c = scount[i];
        sbase[i] = c ? atomicAdd(&cursors[b * 2 * TILES + i], c) : 0u;
    }
    __syncthreads();
    #pragma unroll
    for (int i = 0; i < 8; ++i) {
        int binl = bin8[i];
        if (binl < 0) continue;
        unsigned idx = sbase[binl] + atomicAdd(&scur[binl], 1u);
        if (idx < (unsigned)CAP)
            items[(size_t)(b * 2 * TILES + binl) * CAP + idx] = pay[i];
    }
}

// One block per bin (b,t,tile). LDS tile 33x65 u64 per polarity field
// (0=pos, 1=neg), packing (w<<32 | s) at 2^18 fixed point. Interior pixels
// finalize in-LDS (f32, eps pre-scaled); edge pixels stored (no atomics)
// to the tile's private strip; bound gathers.
__global__ __launch_bounds__(256) void accum_kernel(
    const unsigned long long* __restrict__ items,
    const unsigned* __restrict__ cursors,
    unsigned long long* __restrict__ bndE,
    double* __restrict__ accL, double* __restrict__ accN) {
    constexpr int TPX = (TH + 1) * (TW + 1);      // 2145
    __shared__ unsigned long long sacc[2 * TPX];  // 34,320 B -> 4 blocks/CU
    __shared__ double sm[8];
    int tid = threadIdx.x;
    for (int i = tid; i < 2 * TPX; i += 256) sacc[i] = 0ull;
    __syncthreads();

    int bin = blockIdx.x;
    int b = bin / (2 * TILES);
    int loc = bin - b * (2 * TILES);
    int t = loc / TILES;
    int tile = loc - t * TILES;
    int y0 = (tile / TILES_X) * TH;
    int x0 = (tile % TILES_X) * TW;
    int cnt = (int)min(cursors[bin], (unsigned)CAP);
    const unsigned long long* bi = items + (size_t)bin * CAP;

    for (int i = tid; i < cnt; i += 256) {
        unsigned long long v = bi[i];
        unsigned uy = (unsigned)(v >> 40);
        unsigned ux = (unsigned)(v >> 16) & 0xFFFFFFu;
        float wy = (float)uy * (1.0f / 4096.0f) - 512.0f;
        float wx = (float)ux * (1.0f / 4096.0f) - 512.0f;
        int fyi = (int)(uy >> 12) - 512;
        int fxi = (int)(ux >> 12) - 512;
        float sw = (float)((unsigned)(v >> 2) & 0x3FFFu) * (1.0f / 16383.0f);
        int f = ((v >> 1) & 1) ? 0 : 1;  // pol=1 -> pos field
        #pragma unroll
        for (int dy = 0; dy < 2; ++dy) {
            int ry = fyi + dy, ly = ry - y0;
            if (ry < 0 || ry >= H || ly < 0 || ly > TH) continue;
            float wfy = 1.0f - fabsf(wy - (float)ry);
            #pragma unroll
            for (int dx = 0; dx < 2; ++dx) {
                int rx = fxi + dx, lx = rx - x0;
                if (rx < 0 || rx >= W || lx < 0 || lx > TW) continue;
                float wgt = wfy * (1.0f - fabsf(wx - (float)rx));
                int px = ly * (TW + 1) + lx;
                unsigned w18 = __float2uint_rn(wgt * PSCALE);
                unsigned s18 = __float2uint_rn(wgt * sw * PSCALE);
                atomicAdd(&sacc[f * TPX + px],
                          ((unsigned long long)w18 << 32) | s18);
            }
        }
    }
    __syncthreads();

    float lf = 0.0f;
    int nzi = 0;
    unsigned long long* eb = bndE + (size_t)bin * EDGE_PX * 2;
    for (int p = tid; p < TPX; p += 256) {
        int ly = p / (TW + 1), lx = p - ly * (TW + 1);
        unsigned long long vp = sacc[p];
        unsigned long long vn = sacc[TPX + p];
        // Edge classification (rows own corners).
        int slot = -1;
        if (ly == 0)           slot = lx;                        // seg0
        else if (ly == TH)     slot = (TW + 1) + lx;             // seg1
        else if (lx == 0)      slot = 2 * (TW + 1) + (ly - 1);   // seg2
        else if (lx == TW)     slot = 2 * (TW + 1) + (TH - 1) + (ly - 1);
        if (slot >= 0) {
            eb[(size_t)slot * 2]     = vp;   // unconditional: buffer unzeroed
            eb[(size_t)slot * 2 + 1] = vn;
        } else {
            // scaled domain: (s/PS)/(w/PS+EPS) == s/(w+PS*EPS)
            float a = (float)(unsigned)vp / ((float)(unsigned)(vp >> 32) + EPS_S);
            float c = (float)(unsigned)vn / ((float)(unsigned)(vn >> 32) + EPS_S);
            lf += a * a + c * c;
            nzi += ((vp | vn) >> 32) != 0ull;
        }
    }
    double lt = blk_reduce((double)lf, sm);
    double nt = blk_reduce((double)nzi, sm);
    if (tid == 0) {
        int j = b * 2 + t;
        accL[j * TILES + tile] = lt;   // distinct slot: NO atomics
        accN[j * TILES + tile] = nt;
    }
}

// Fused: blocks [0, SM_BLK) smooth; [SM_BLK, +BND_BLK*16) bound.
// Bound gathers the line pixels; row-lines own corners; col entries with
// y%TH==0 contribute zero. Smooth rides in the idle capacity (bound is
// tiny-LDS, low-BW).
__global__ __launch_bounds__(256) void bound_smooth_kernel(
    const unsigned long long* __restrict__ bndE, const float* __restrict__ flow,
    double* __restrict__ bndL, double* __restrict__ bndN,
    double* __restrict__ smP) {
    __shared__ double sm[8];
    int tid = threadIdx.x;

    if (blockIdx.x < SM_BLK) {
        // ---- smooth path ----
        int sb = blockIdx.x;
        double sdx = 0.0, sdy = 0.0, sdr = 0.0, sur = 0.0;
        int stride = SM_BLK * 256;
        for (int i = sb * 256 + tid; i < B * HW; i += stride) {
            int b = i / HW;
            int rem = i - b * HW;
            int y = rem / W;
            int x = rem - y * W;
            const float* fx = flow + (size_t)(b * 2 + 0) * HW;
            const float* fy = flow + (size_t)(b * 2 + 1) * HW;
            float f00 = fx[rem], g00 = fy[rem];
            bool xe = (x + 1) < W;
            bool ye = (y + 1) < H;
            if (xe) {
                float f01 = fx[rem + 1], g01 = fy[rem + 1];
                sdx += (double)charb(f00 - f01, g00 - g01);
                if (ye) {
                    float f10 = fx[rem + W], g10 = fy[rem + W];
                    float f11 = fx[rem + W + 1], g11 = fy[rem + W + 1];
                    sdy += (double)charb(f00 - f10, g00 - g10);
                    sdr += (double)charb(f00 - f11, g00 - g11);
                    sur += (double)charb(f10 - f01, g10 - g01);
                }
            } else if (ye) {
                float f10 = fx[rem + W], g10 = fy[rem + W];
                sdy += (double)charb(f00 - f10, g00 - g10);
            }
        }
        double tt;
        tt = blk_reduce(sdx, sm); if (tid == 0) smP[sb * 4 + 0] = tt;
        tt = blk_reduce(sdy, sm); if (tid == 0) smP[sb * 4 + 1] = tt;
        tt = blk_reduce(sdr, sm); if (tid == 0) smP[sb * 4 + 2] = tt;
        tt = blk_reduce(sur, sm); if (tid == 0) smP[sb * 4 + 3] = tt;
        return;
    }

    // ---- bound path ----
    int local = blockIdx.x - SM_BLK;
    int j = local / BND_BLK;
    int bx = local - j * BND_BLK;
    int b = j >> 1, t = j & 1;
    const unsigned long long* jb =
        bndE + (size_t)(b * 2 * TILES + t * TILES) * EDGE_PX * 2;

    float lf = 0.0f;
    int nzi = 0;
    for (int p = bx * 256 + tid; p < BPX; p += BND_BLK * 256) {
        unsigned long long vp = 0ull, vn = 0ull;
        if (p < TILES_Y * W) {
            int k = p / W, x = p - k * W;
            int m = x >> 6, lx = x & 63;
            const unsigned long long* e;
            e = jb + ((size_t)(k * TILES_X + m) * EDGE_PX + lx) * 2;      // seg0
            vp += e[0]; vn += e[1];
            if (k > 0) {
                e = jb + ((size_t)((k - 1) * TILES_X + m) * EDGE_PX + (TW + 1) + lx) * 2;
                vp += e[0]; vn += e[1];
            }
            if (lx == 0 && m > 0) {
                e = jb + ((size_t)(k * TILES_X + m - 1) * EDGE_PX + TW) * 2;
                vp += e[0]; vn += e[1];
                if (k > 0) {
                    e = jb + ((size_t)((k - 1) * TILES_X + m - 1) * EDGE_PX + 2 * TW + 1) * 2;
                    vp += e[0]; vn += e[1];
                }
            }
        } else {
            int q = p - TILES_Y * W;
            int m = q / H, y = q - m * H;
            int r = y / TH, ly = y - r * TH;
            if (ly != 0) {
                const unsigned long long* e;
                e = jb + ((size_t)(r * TILES_X + m) * EDGE_PX + 2 * (TW + 1) + ly - 1) * 2;
                vp += e[0]; vn += e[1];
                if (m > 0) {
                    e = jb + ((size_t)(r * TILES_X + m - 1) * EDGE_PX
                              + 2 * (TW + 1) + (TH - 1) + ly - 1) * 2;
                    vp += e[0]; vn += e[1];
                }
            }
        }
        float a = (float)(unsigned)vp / ((float)(unsigned)(vp >> 32) + EPS_S);
        float c = (float)(unsigned)vn / ((float)(unsigned)(vn >> 32) + EPS_S);
        lf += a * a + c * c;
        nzi += ((vp | vn) >> 32) != 0ull;
    }
    double lt = blk_reduce((double)lf, sm);
    double nt = blk_reduce((double)nzi, sm);
    if (tid == 0) {
        bndL[j * BND_BLK + bx] = lt;
        bndN[j * BND_BLK + bx] = nt;
    }
}

// One block, 256 threads: 16 threads per job reduce accL/N + bndL/N
// (width-16 shfl); whole block reduces the 4 smooth sums.
__global__ __launch_bounds__(256) void final_kernel(
    const double* __restrict__ accL, const double* __restrict__ accN,
    const double* __restrict__ bndL, const double* __restrict__ bndN,
    const double* __restrict__ smP, float* __restrict__ out) {
    __shared__ double sj[16];
    __shared__ double sm[8];
    int tid = threadIdx.x;
    int j = tid >> 4, s = tid & 15;
    double l = 0.0, nz = 0.0;
    for (int i = s; i < TILES; i += 16) {
        l += accL[j * TILES + i];
        nz += accN[j * TILES + i];
    }
    for (int i = s; i < BND_BLK; i += 16) {
        l += bndL[j * BND_BLK + i];
        nz += bndN[j * BND_BLK + i];
    }
    #pragma unroll
    for (int o = 8; o > 0; o >>= 1) {
        l += __shfl_down(l, o, 16);
        nz += __shfl_down(nz, o, 16);
    }
    if (s == 0) sj[j] = l / nz;

    double c[4] = {0.0, 0.0, 0.0, 0.0};
    for (int i = tid; i < SM_BLK; i += 256) {
        #pragma unroll
        for (int k = 0; k < 4; ++k) c[k] += smP[i * 4 + k];
    }
    double s0 = blk_reduce(c[0], sm);
    double s1 = blk_reduce(c[1], sm);
    double s2 = blk_reduce(c[2], sm);
    double s3 = blk_reduce(c[3], sm);
    __syncthreads();
    if (tid == 0) {
        double loss = 0.0;
        for (int q = 0; q < 16; ++q) loss += sj[q];
        double ndx = (double)B * H * (W - 1);
        double ndy = (double)B * (H - 1) * W;
        double ndd = (double)B * (H - 1) * (W - 1);
        double smooth = (s0 / ndx + s1 / ndy + s2 / ndd + s3 / ndd) * 0.25;
        out[0] = (float)(loss + 0.001 * smooth);
    }
}

extern "C" void kernel_launch(void* const* d_in, const int* in_sizes, int n_in,
                              void* d_out, int out_size, void* d_ws, size_t ws_size,
                              hipStream_t stream) {
    const float* flow = (const float*)d_in[0];
    const float* ts   = (const float*)d_in[1];
    const int*   ys   = (const int*)d_in[2];
    const int*   xs   = (const int*)d_in[3];
    const int*   pol  = (const int*)d_in[4];
    float* out = (float*)d_out;

    char* ws = (char*)d_ws;
    double* accL = (double*)(ws + ACCL_OFF);
    double* accN = (double*)(ws + ACCN_OFF);
    double* bndL = (double*)(ws + BNDL_OFF);
    double* bndN = (double*)(ws + BNDN_OFF);
    double* smP  = (double*)(ws + SMP_OFF);
    unsigned* cursors = (unsigned*)(ws + CUR_OFF);
    unsigned long long* bndE = (unsigned long long*)(ws + BNDE_OFF);
    unsigned long long* items = (unsigned long long*)(ws + ITEMS_OFF);

    // Only cursors need zeroing.
    hipMemsetAsync(cursors, 0, (size_t)NBINS * 4, stream);
    scatter_kernel<<<SC_BLOCKS, 256, 0, stream>>>(
        flow, ts, ys, xs, pol, items, cursors);
    accum_kernel<<<NBINS, 256, 0, stream>>>(items, cursors, bndE, accL, accN);
    bound_smooth_kernel<<<SM_BLK + BND_BLK * 16, 256, 0, stream>>>(
        bndE, flow, bndL, bndN, smP);
    final_kernel<<<1, 256, 0, stream>>>(accL, accN, bndL, bndN, smP, out);
}

// Round 12
// 144.037 us; speedup vs baseline: 1.0664x; 1.0664x over previous
//
#include <hip/hip_runtime.h>

// EventWarping: contrast-maximization loss for event-camera flow.
// flow [B,2,H,W] f32, ts [B,N,1] f32, ys/xs/pol [B,N] i32 -> scalar f32.
//
// Round 12: r8 (best, 145.7us) restored with ONE delta: smooth now rides in
// the ACCUM launch (not scatter). Rationale: scatter+smooth fusion summed
// (both memory-latency-bound); accum is LDS-atomic-bound -> complementary
// pipes, real overlap expected. r11's separate bound_smooth regressed
// (smooth serialized after accum).

constexpr int H = 480, W = 640, HW = H * W;
constexpr int B = 8, N = 131072;
constexpr float FLOW_SCALING = 640.0f;
constexpr float EPS = 1e-9f;

constexpr int TH = 32, TW = 64;            // tile size
constexpr int TILES_Y = H / TH;            // 15
constexpr int TILES_X = W / TW;            // 10
constexpr int TILES = TILES_Y * TILES_X;   // 150
constexpr int NBINS = B * 2 * TILES;       // 2400 (b, tref, tile)
constexpr int CAP = 3072;                  // slots per bin (mean ~873, ~74 sigma)

constexpr float PSCALE = 262144.0f;        // 2^18 fixed point
constexpr float EPS_S = PSCALE * EPS;      // eps in scaled domain

constexpr int BND_BLK = 56;                // bound grid.x
constexpr int SM_BLK = 512;                // smooth blocks (fused into accum)
constexpr int SC_BLOCKS = 1024;            // scatter grid (128 per batch)

// Per-tile edge strip: seg0 ly=0 (65), seg1 ly=TH (65), seg2 lx=0,ly=1..TH-1
// (31), seg3 lx=TW,ly=1..TH-1 (31) => 192 entries x {pos,neg} u64.
constexpr int EDGE_PX = 2 * (TW + 1) + 2 * (TH - 1);   // 192

// Line-pixel index space per job: row-lines k*W+x, col-lines TILES_Y*W+m*H+y.
constexpr int BPX = TILES_Y * W + TILES_X * H;   // 14400

// Workspace layout:
constexpr size_t ACCL_OFF = 0;                                        // f64[16][150]
constexpr size_t ACCN_OFF = ACCL_OFF + (size_t)16 * TILES * 8;
constexpr size_t BNDL_OFF = ACCN_OFF + (size_t)16 * TILES * 8;
constexpr size_t BNDN_OFF = BNDL_OFF + (size_t)16 * BND_BLK * 8;
constexpr size_t SMP_OFF  = BNDN_OFF + (size_t)16 * BND_BLK * 8;
constexpr size_t CUR_OFF  = SMP_OFF + (size_t)SM_BLK * 4 * 8;
constexpr size_t BNDE_OFF = CUR_OFF + (size_t)NBINS * 4;
constexpr size_t BNDE_BYTES = (size_t)NBINS * EDGE_PX * 2 * 8;        // 7.37MB
constexpr size_t ITEMS_OFF = BNDE_OFF + BNDE_BYTES;                   // +59MB items

__device__ inline double blk_reduce(double v, double* sm) {
    __syncthreads();
    #pragma unroll
    for (int o = 32; o > 0; o >>= 1) v += __shfl_down(v, o, 64);
    int lane = threadIdx.x & 63;
    int wid  = threadIdx.x >> 6;
    if (lane == 0) sm[wid] = v;
    __syncthreads();
    double r = 0.0;
    if (threadIdx.x == 0) {
        int nw = (int)(blockDim.x >> 6);
        for (int w2 = 0; w2 < nw; ++w2) r += sm[w2];
    }
    return r;  // thread 0 only
}

// Local bin id (tref*TILES + tile) from the PACKED payload, so count and
// placement can never disagree.
__device__ inline int bin_from_payload(unsigned long long v) {
    int t = (int)(v & 1);
    int fyi = (int)((unsigned)(v >> 40) >> 12) - 512;
    int fxi = (int)(((unsigned)(v >> 16) & 0xFFFFFFu) >> 12) - 512;
    int cy = min(max(fyi, 0), H - 1);
    int cx = min(max(fxi, 0), W - 1);
    return t * TILES + (cy >> 5) * TILES_X + (cx >> 6);
}

__device__ inline float charb(float a, float b) {
    return sqrtf(a * a + b * b + 1e-6f);
}

// Pure scatter: batch = blockIdx&7 (XCD pin), 1024 events/block (4/thread,
// int4/float4 loads). Payload u64: [63:40] (wy+512)*4096 rn,
// [39:16] (wx+512)*4096 rn, [15:2] sw*16383 rn, [1] pol, [0] tref.
__global__ __launch_bounds__(256) void scatter_kernel(
    const float* __restrict__ flow, const float* __restrict__ ts,
    const int* __restrict__ ys, const int* __restrict__ xs,
    const int* __restrict__ pol,
    unsigned long long* __restrict__ items, unsigned* __restrict__ cursors) {
    __shared__ unsigned scount[2 * TILES];
    __shared__ unsigned sbase[2 * TILES];
    __shared__ unsigned scur[2 * TILES];
    int tid = threadIdx.x;
    for (int i = tid; i < 2 * TILES; i += 256) { scount[i] = 0; scur[i] = 0; }
    __syncthreads();

    int b = blockIdx.x & 7;
    int chunk = blockIdx.x >> 3;          // 0..127
    int eb0 = b * N + chunk * 1024;       // 16B aligned
    const float* fb = flow + (size_t)b * 2 * HW;

    int4   yv = ((const int4*)(ys + eb0))[tid];
    int4   xv = ((const int4*)(xs + eb0))[tid];
    int4   pv = ((const int4*)(pol + eb0))[tid];
    float4 tv = ((const float4*)(ts + eb0))[tid];
    int y4[4] = {yv.x, yv.y, yv.z, yv.w};
    int x4[4] = {xv.x, xv.y, xv.z, xv.w};
    int p4[4] = {pv.x, pv.y, pv.z, pv.w};
    float t4[4] = {tv.x, tv.y, tv.z, tv.w};

    float fx4[4], fy4[4];
    #pragma unroll
    for (int k = 0; k < 4; ++k) {
        int flat = y4[k] * W + x4[k];
        fx4[k] = fb[flat];
        fy4[k] = fb[HW + flat];
    }

    unsigned long long pay[8];
    int bin8[8];
    #pragma unroll
    for (int k = 0; k < 4; ++k) {
        float t0 = t4[k];
        #pragma unroll
        for (int t = 0; t < 2; ++t) {
            float dt = (t == 0 ? 1.0f : 0.0f) - t0;
            float sw = (t == 0) ? t0 : 1.0f - t0;
            float wy = (float)y4[k] + dt * fy4[k] * FLOW_SCALING;
            float wx = (float)x4[k] + dt * fx4[k] * FLOW_SCALING;
            unsigned long long v = ~0ull;  // sentinel = invalid
            int binl = -1;
            if (wy >= -1.0f && wy < (float)H && wx >= -1.0f && wx < (float)W) {
                unsigned uy = __float2uint_rn((wy + 512.0f) * 4096.0f);
                unsigned ux = __float2uint_rn((wx + 512.0f) * 4096.0f);
                unsigned usw = __float2uint_rn(sw * 16383.0f);
                v = ((unsigned long long)uy << 40) |
                    ((unsigned long long)ux << 16) |
                    ((unsigned long long)usw << 2) |
                    ((unsigned long long)(p4[k] != 0) << 1) |
                    (unsigned long long)t;
                binl = bin_from_payload(v);
                atomicAdd(&scount[binl], 1u);
            }
            pay[k * 2 + t] = v;
            bin8[k * 2 + t] = binl;
        }
    }
    __syncthreads();
    for (int i = tid; i < 2 * TILES; i += 256) {
        unsigned c = scount[i];
        sbase[i] = c ? atomicAdd(&cursors[b * 2 * TILES + i], c) : 0u;
    }
    __syncthreads();
    #pragma unroll
    for (int i = 0; i < 8; ++i) {
        int binl = bin8[i];
        if (binl < 0) continue;
        unsigned idx = sbase[binl] + atomicAdd(&scur[binl], 1u);
        if (idx < (unsigned)CAP)
            items[(size_t)(b * 2 * TILES + binl) * CAP + idx] = pay[i];
    }
}

// Fused: blocks [0, SM_BLK) smooth (HBM-stream + VALU); [SM_BLK, +NBINS)
// accum (LDS-atomic-bound) — complementary pipes, expected real overlap.
// Accum: one block per bin (b,t,tile). LDS tile 33x65 u64 per polarity
// field, packing (w<<32 | s) at 2^18 fixed point. Interior pixels finalize
// in-LDS (f32, eps pre-scaled); edge pixels stored (no atomics) to the
// tile's private strip; bound gathers.
__global__ __launch_bounds__(256) void accum_smooth_kernel(
    const unsigned long long* __restrict__ items,
    const unsigned* __restrict__ cursors, const float* __restrict__ flow,
    unsigned long long* __restrict__ bndE,
    double* __restrict__ accL, double* __restrict__ accN,
    double* __restrict__ smP) {
    constexpr int TPX = (TH + 1) * (TW + 1);      // 2145
    __shared__ unsigned long long sacc[2 * TPX];  // 34,320 B
    __shared__ double sm[8];
    int tid = threadIdx.x;

    if (blockIdx.x < SM_BLK) {
        // ---- smooth path ----
        int sb = blockIdx.x;
        double sdx = 0.0, sdy = 0.0, sdr = 0.0, sur = 0.0;
        int stride = SM_BLK * 256;
        for (int i = sb * 256 + tid; i < B * HW; i += stride) {
            int b = i / HW;
            int rem = i - b * HW;
            int y = rem / W;
            int x = rem - y * W;
            const float* fx = flow + (size_t)(b * 2 + 0) * HW;
            const float* fy = flow + (size_t)(b * 2 + 1) * HW;
            float f00 = fx[rem], g00 = fy[rem];
            bool xe = (x + 1) < W;
            bool ye = (y + 1) < H;
            if (xe) {
                float f01 = fx[rem + 1], g01 = fy[rem + 1];
                sdx += (double)charb(f00 - f01, g00 - g01);
                if (ye) {
                    float f10 = fx[rem + W], g10 = fy[rem + W];
                    float f11 = fx[rem + W + 1], g11 = fy[rem + W + 1];
                    sdy += (double)charb(f00 - f10, g00 - g10);
                    sdr += (double)charb(f00 - f11, g00 - g11);
                    sur += (double)charb(f10 - f01, g10 - g01);
                }
            } else if (ye) {
                float f10 = fx[rem + W], g10 = fy[rem + W];
                sdy += (double)charb(f00 - f10, g00 - g10);
            }
        }
        double tt;
        tt = blk_reduce(sdx, sm); if (tid == 0) smP[sb * 4 + 0] = tt;
        tt = blk_reduce(sdy, sm); if (tid == 0) smP[sb * 4 + 1] = tt;
        tt = blk_reduce(sdr, sm); if (tid == 0) smP[sb * 4 + 2] = tt;
        tt = blk_reduce(sur, sm); if (tid == 0) smP[sb * 4 + 3] = tt;
        return;
    }

    // ---- accum path ----
    for (int i = tid; i < 2 * TPX; i += 256) sacc[i] = 0ull;
    __syncthreads();

    int bin = blockIdx.x - SM_BLK;
    int b = bin / (2 * TILES);
    int loc = bin - b * (2 * TILES);
    int t = loc / TILES;
    int tile = loc - t * TILES;
    int y0 = (tile / TILES_X) * TH;
    int x0 = (tile % TILES_X) * TW;
    int cnt = (int)min(cursors[bin], (unsigned)CAP);
    const unsigned long long* bi = items + (size_t)bin * CAP;

    for (int i = tid; i < cnt; i += 256) {
        unsigned long long v = bi[i];
        unsigned uy = (unsigned)(v >> 40);
        unsigned ux = (unsigned)(v >> 16) & 0xFFFFFFu;
        float wy = (float)uy * (1.0f / 4096.0f) - 512.0f;
        float wx = (float)ux * (1.0f / 4096.0f) - 512.0f;
        int fyi = (int)(uy >> 12) - 512;
        int fxi = (int)(ux >> 12) - 512;
        float sw = (float)((unsigned)(v >> 2) & 0x3FFFu) * (1.0f / 16383.0f);
        int f = ((v >> 1) & 1) ? 0 : 1;  // pol=1 -> pos field
        #pragma unroll
        for (int dy = 0; dy < 2; ++dy) {
            int ry = fyi + dy, ly = ry - y0;
            if (ry < 0 || ry >= H || ly < 0 || ly > TH) continue;
            float wfy = 1.0f - fabsf(wy - (float)ry);
            #pragma unroll
            for (int dx = 0; dx < 2; ++dx) {
                int rx = fxi + dx, lx = rx - x0;
                if (rx < 0 || rx >= W || lx < 0 || lx > TW) continue;
                float wgt = wfy * (1.0f - fabsf(wx - (float)rx));
                int px = ly * (TW + 1) + lx;
                unsigned w18 = __float2uint_rn(wgt * PSCALE);
                unsigned s18 = __float2uint_rn(wgt * sw * PSCALE);
                atomicAdd(&sacc[f * TPX + px],
                          ((unsigned long long)w18 << 32) | s18);
            }
        }
    }
    __syncthreads();

    float lf = 0.0f;
    int nzi = 0;
    unsigned long long* eb = bndE + (size_t)bin * EDGE_PX * 2;
    for (int p = tid; p < TPX; p += 256) {
        int ly = p / (TW + 1), lx = p - ly * (TW + 1);
        unsigned long long vp = sacc[p];
        unsigned long long vn = sacc[TPX + p];
        // Edge classification (rows own corners).
        int slot = -1;
        if (ly == 0)           slot = lx;                        // seg0
        else if (ly == TH)     slot = (TW + 1) + lx;             // seg1
        else if (lx == 0)      slot = 2 * (TW + 1) + (ly - 1);   // seg2
        else if (lx == TW)     slot = 2 * (TW + 1) + (TH - 1) + (ly - 1);
        if (slot >= 0) {
            eb[(size_t)slot * 2]     = vp;   // unconditional: buffer unzeroed
            eb[(size_t)slot * 2 + 1] = vn;
        } else {
            // scaled domain: (s/PS)/(w/PS+EPS) == s/(w+PS*EPS)
            float a = (float)(unsigned)vp / ((float)(unsigned)(vp >> 32) + EPS_S);
            float c = (float)(unsigned)vn / ((float)(unsigned)(vn >> 32) + EPS_S);
            lf += a * a + c * c;
            nzi += ((vp | vn) >> 32) != 0ull;
        }
    }
    double lt = blk_reduce((double)lf, sm);
    double nt = blk_reduce((double)nzi, sm);
    if (tid == 0) {
        int j = b * 2 + t;
        accL[j * TILES + tile] = lt;   // distinct slot: NO atomics
        accN[j * TILES + tile] = nt;
    }
}

// Gather-reduce the line pixels. grid (BND_BLK, 16). Row-lines own corners;
// col entries with y%TH==0 contribute zero.
__global__ __launch_bounds__(256) void bound_kernel(
    const unsigned long long* __restrict__ bndE,
    double* __restrict__ bndL, double* __restrict__ bndN) {
    __shared__ double sm[8];
    int j = blockIdx.y;
    int b = j >> 1, t = j & 1;
    const unsigned long long* jb =
        bndE + (size_t)(b * 2 * TILES + t * TILES) * EDGE_PX * 2;

    float lf = 0.0f;
    int nzi = 0;
    for (int p = blockIdx.x * blockDim.x + threadIdx.x; p < BPX;
         p += gridDim.x * blockDim.x) {
        unsigned long long vp = 0ull, vn = 0ull;
        if (p < TILES_Y * W) {
            int k = p / W, x = p - k * W;
            int m = x >> 6, lx = x & 63;
            const unsigned long long* e;
            e = jb + ((size_t)(k * TILES_X + m) * EDGE_PX + lx) * 2;      // seg0
            vp += e[0]; vn += e[1];
            if (k > 0) {
                e = jb + ((size_t)((k - 1) * TILES_X + m) * EDGE_PX + (TW + 1) + lx) * 2;
                vp += e[0]; vn += e[1];
            }
            if (lx == 0 && m > 0) {
                e = jb + ((size_t)(k * TILES_X + m - 1) * EDGE_PX + TW) * 2;
                vp += e[0]; vn += e[1];
                if (k > 0) {
                    e = jb + ((size_t)((k - 1) * TILES_X + m - 1) * EDGE_PX + 2 * TW + 1) * 2;
                    vp += e[0]; vn += e[1];
                }
            }
        } else {
            int q = p - TILES_Y * W;
            int m = q / H, y = q - m * H;
            int r = y / TH, ly = y - r * TH;
            if (ly != 0) {
                const unsigned long long* e;
                e = jb + ((size_t)(r * TILES_X + m) * EDGE_PX + 2 * (TW + 1) + ly - 1) * 2;
                vp += e[0]; vn += e[1];
                if (m > 0) {
                    e = jb + ((size_t)(r * TILES_X + m - 1) * EDGE_PX
                              + 2 * (TW + 1) + (TH - 1) + ly - 1) * 2;
                    vp += e[0]; vn += e[1];
                }
            }
        }
        float a = (float)(unsigned)vp / ((float)(unsigned)(vp >> 32) + EPS_S);
        float c = (float)(unsigned)vn / ((float)(unsigned)(vn >> 32) + EPS_S);
        lf += a * a + c * c;
        nzi += ((vp | vn) >> 32) != 0ull;
    }
    double lt = blk_reduce((double)lf, sm);
    double nt = blk_reduce((double)nzi, sm);
    if (threadIdx.x == 0) {
        bndL[j * BND_BLK + blockIdx.x] = lt;
        bndN[j * BND_BLK + blockIdx.x] = nt;
    }
}

// One block, 256 threads: 16 threads per job reduce accL/N + bndL/N
// (width-16 shfl); whole block reduces the 4 smooth sums.
__global__ __launch_bounds__(256) void final_kernel(
    const double* __restrict__ accL, const double* __restrict__ accN,
    const double* __restrict__ bndL, const double* __restrict__ bndN,
    const double* __restrict__ smP, float* __restrict__ out) {
    __shared__ double sj[16];
    __shared__ double sm[8];
    int tid = threadIdx.x;
    int j = tid >> 4, s = tid & 15;
    double l = 0.0, nz = 0.0;
    for (int i = s; i < TILES; i += 16) {
        l += accL[j * TILES + i];
        nz += accN[j * TILES + i];
    }
    for (int i = s; i < BND_BLK; i += 16) {
        l += bndL[j * BND_BLK + i];
        nz += bndN[j * BND_BLK + i];
    }
    #pragma unroll
    for (int o = 8; o > 0; o >>= 1) {
        l += __shfl_down(l, o, 16);
        nz += __shfl_down(nz, o, 16);
    }
    if (s == 0) sj[j] = l / nz;

    double c[4] = {0.0, 0.0, 0.0, 0.0};
    for (int i = tid; i < SM_BLK; i += 256) {
        #pragma unroll
        for (int k = 0; k < 4; ++k) c[k] += smP[i * 4 + k];
    }
    double s0 = blk_reduce(c[0], sm);
    double s1 = blk_reduce(c[1], sm);
    double s2 = blk_reduce(c[2], sm);
    double s3 = blk_reduce(c[3], sm);
    __syncthreads();
    if (tid == 0) {
        double loss = 0.0;
        for (int q = 0; q < 16; ++q) loss += sj[q];
        double ndx = (double)B * H * (W - 1);
        double ndy = (double)B * (H - 1) * W;
        double ndd = (double)B * (H - 1) * (W - 1);
        double smooth = (s0 / ndx + s1 / ndy + s2 / ndd + s3 / ndd) * 0.25;
        out[0] = (float)(loss + 0.001 * smooth);
    }
}

extern "C" void kernel_launch(void* const* d_in, const int* in_sizes, int n_in,
                              void* d_out, int out_size, void* d_ws, size_t ws_size,
                              hipStream_t stream) {
    const float* flow = (const float*)d_in[0];
    const float* ts   = (const float*)d_in[1];
    const int*   ys   = (const int*)d_in[2];
    const int*   xs   = (const int*)d_in[3];
    const int*   pol  = (const int*)d_in[4];
    float* out = (float*)d_out;

    char* ws = (char*)d_ws;
    double* accL = (double*)(ws + ACCL_OFF);
    double* accN = (double*)(ws + ACCN_OFF);
    double* bndL = (double*)(ws + BNDL_OFF);
    double* bndN = (double*)(ws + BNDN_OFF);
    double* smP  = (double*)(ws + SMP_OFF);
    unsigned* cursors = (unsigned*)(ws + CUR_OFF);
    unsigned long long* bndE = (unsigned long long*)(ws + BNDE_OFF);
    unsigned long long* items = (unsigned long long*)(ws + ITEMS_OFF);

    // Only cursors need zeroing.
    hipMemsetAsync(cursors, 0, (size_t)NBINS * 4, stream);
    scatter_kernel<<<SC_BLOCKS, 256, 0, stream>>>(
        flow, ts, ys, xs, pol, items, cursors);
    accum_smooth_kernel<<<SM_BLK + NBINS, 256, 0, stream>>>(
        items, cursors, flow, bndE, accL, accN, smP);
    bound_kernel<<<dim3(BND_BLK, 16), 256, 0, stream>>>(bndE, bndL, bndN);
    final_kernel<<<1, 256, 0, stream>>>(accL, accN, bndL, bndN, smP, out);
}